// Round 2
// 587.074 us; speedup vs baseline: 1.2840x; 1.2840x over previous
//
#include <hip/hip_runtime.h>

#define BB 4
#define TT 4096
#define NH 16
#define HK 128
#define PE 64
#define DD 1024      // NH * PE
#define RK 16        // PHI_RANK
#define MD 2048      // MODEL_DIM
#define NC 64        // number of T-chunks
#define CS 64        // chunk size (NC*CS == TT)

// ---------------------------------------------------------------------------
// K1: u[b,t,r] = (per-HEAD-L2-normalized hidden) @ W1     (b*t flat = 16384)
//
// Token-per-lane, K-split across 4 waves (512 dims = 4 heads each).
// Each head = 128 dims = 2 consecutive 64-dim K-tiles; per-head partial dots
// accumulate in accH/ssH, closed with rsqrt every 2nd tile into accF
// (normalization is linear per head, so post-dot scaling is exact).
// Hidden tile staged to LDS with XOR swizzle (conflict-free column reads);
// W1 slice staged to LDS, read wave-uniform (bank broadcast).
// Next-tile global loads issued before current-tile compute (latency hide).
// ---------------------------------------------------------------------------
__global__ __launch_bounds__(256) void k1_u(const float* __restrict__ hidden,
                                            const float* __restrict__ W1,
                                            float* __restrict__ u) {
  __shared__ float hs[4 * 64 * 64];   // 64 KB: per-wave hidden tile, swizzled
  __shared__ float w1t[4 * 64 * RK];  // 16 KB: per-wave W1 row slice

  const int tid  = threadIdx.x;
  const int lane = tid & 63;          // token within block
  const int kg   = tid >> 6;          // wave id = K-group
  const int tok0 = blockIdx.x * 64;

  float* hw = hs  + kg * (64 * 64);
  float* ww = w1t + kg * (64 * RK);
  const int kbase = kg * 512;         // this wave's dim-range start (4 heads)

  float4 hreg[16];
  float4 wreg[4];

  // prologue: issue loads for dc = 0
#pragma unroll
  for (int it = 0; it < 16; ++it) {
    int idx = it * 64 + lane;
    int tr = idx >> 4, q = idx & 15;
    hreg[it] = *(const float4*)(hidden + (size_t)(tok0 + tr) * MD + kbase + q * 4);
  }
#pragma unroll
  for (int it = 0; it < 4; ++it) {
    int idx = it * 64 + lane;
    wreg[it] = *(const float4*)(W1 + (size_t)kbase * RK + idx * 4);
  }

  float ssH = 0.f;                    // current head sum-of-squares
  float accH[RK];                     // current head partial dots
  float accF[RK];                     // normalized accumulated result
#pragma unroll
  for (int r = 0; r < RK; ++r) { accH[r] = 0.f; accF[r] = 0.f; }

  for (int dc = 0; dc < 8; ++dc) {
    // write staged regs to LDS (swizzled: column read later is conflict-free)
#pragma unroll
    for (int it = 0; it < 16; ++it) {
      int idx = it * 64 + lane;
      int tr = idx >> 4, q = idx & 15;
      int base = tr * 64;
      int sw = tr & 31;
      hw[base + ((q * 4 + 0) ^ sw)] = hreg[it].x;
      hw[base + ((q * 4 + 1) ^ sw)] = hreg[it].y;
      hw[base + ((q * 4 + 2) ^ sw)] = hreg[it].z;
      hw[base + ((q * 4 + 3) ^ sw)] = hreg[it].w;
    }
#pragma unroll
    for (int it = 0; it < 4; ++it) {
      int idx = it * 64 + lane;
      *(float4*)(ww + idx * 4) = wreg[it];
    }

    // issue next-tile global loads (overlap with compute below)
    if (dc < 7) {
      const int kb = kbase + (dc + 1) * 64;
#pragma unroll
      for (int it = 0; it < 16; ++it) {
        int idx = it * 64 + lane;
        int tr = idx >> 4, q = idx & 15;
        hreg[it] = *(const float4*)(hidden + (size_t)(tok0 + tr) * MD + kb + q * 4);
      }
#pragma unroll
      for (int it = 0; it < 4; ++it) {
        int idx = it * 64 + lane;
        wreg[it] = *(const float4*)(W1 + (size_t)kb * RK + idx * 4);
      }
    }

    // compute on the LDS tile
    const int sw = lane & 31;
    const float* hrow = hw + lane * 64;
#pragma unroll 8
    for (int d = 0; d < 64; ++d) {
      float e = hrow[d ^ sw];
      ssH += e * e;
      const float4* wr = (const float4*)(ww + d * RK);  // wave-uniform -> broadcast
      float4 w0 = wr[0], w1v = wr[1], w2v = wr[2], w3v = wr[3];
      accH[0]  += e * w0.x;  accH[1]  += e * w0.y;  accH[2]  += e * w0.z;  accH[3]  += e * w0.w;
      accH[4]  += e * w1v.x; accH[5]  += e * w1v.y; accH[6]  += e * w1v.z; accH[7]  += e * w1v.w;
      accH[8]  += e * w2v.x; accH[9]  += e * w2v.y; accH[10] += e * w2v.z; accH[11] += e * w2v.w;
      accH[12] += e * w3v.x; accH[13] += e * w3v.y; accH[14] += e * w3v.z; accH[15] += e * w3v.w;
    }

    // head boundary every 2 tiles (128 dims): apply per-head normalization
    if (dc & 1) {
      float inv = rsqrtf(ssH + 1e-6f);
#pragma unroll
      for (int r = 0; r < RK; ++r) { accF[r] += accH[r] * inv; accH[r] = 0.f; }
      ssH = 0.f;
    }
  }

  // cross-wave reduction (reuse hs; stride 17 -> conflict-free writes)
  __syncthreads();
  float* red = hs;
  {
    float* rp = red + (kg * 64 + lane) * 17;
#pragma unroll
    for (int r = 0; r < RK; ++r) rp[r] = accF[r];
  }
  __syncthreads();
  {
    int tok = tid >> 2, rq = tid & 3;
    float o0 = 0.f, o1 = 0.f, o2 = 0.f, o3 = 0.f;
#pragma unroll
    for (int g = 0; g < 4; ++g) {
      const float* rp = red + (g * 64 + tok) * 17;
      o0 += rp[rq * 4 + 0];
      o1 += rp[rq * 4 + 1];
      o2 += rp[rq * 4 + 2];
      o3 += rp[rq * 4 + 3];
    }
    float4 o = make_float4(o0, o1, o2, o3);
    *(float4*)(u + (size_t)(tok0 + tok) * RK + rq * 4) = o;
  }
}

// phi_raw(t, d) = dot(u[b,t,:], W2[:,d]); t<0 -> 0 (causal conv left padding)
__device__ __forceinline__ float phi_raw(const float* __restrict__ ub, int t,
                                         const float* __restrict__ w2r) {
  if (t < 0) return 0.f;
  const float4* up = (const float4*)(ub + (size_t)t * RK);
  float4 u0 = up[0], u1 = up[1], u2 = up[2], u3 = up[3];
  return u0.x * w2r[0]  + u0.y * w2r[1]  + u0.z * w2r[2]  + u0.w * w2r[3]
       + u1.x * w2r[4]  + u1.y * w2r[5]  + u1.z * w2r[6]  + u1.w * w2r[7]
       + u2.x * w2r[8]  + u2.y * w2r[9]  + u2.z * w2r[10] + u2.w * w2r[11]
       + u3.x * w2r[12] + u3.y * w2r[13] + u3.z * w2r[14] + u3.w * w2r[15];
}

// ---------------------------------------------------------------------------
// K2: per-chunk totals of phi_conv over each CS-length chunk.
// grid = BB*NC*4 blocks x 256 threads; thread owns one d channel.
// ---------------------------------------------------------------------------
__global__ __launch_bounds__(256) void k2_csum(const float* __restrict__ u,
                                               const float* __restrict__ W2,
                                               const float* __restrict__ cw,
                                               float* __restrict__ csum) {
  int tid = threadIdx.x;
  int blk = blockIdx.x;
  int dblk = blk & 3;
  int bc = blk >> 2;               // b*NC + chunk
  int chunk = bc & (NC - 1);
  int b = bc >> 6;
  int d = dblk * 256 + tid;

  float w2r[RK];
#pragma unroll
  for (int r = 0; r < RK; ++r) w2r[r] = W2[r * DD + d];
  float c0 = cw[0 * DD + d], c1 = cw[1 * DD + d];
  float c2 = cw[2 * DD + d], c3 = cw[3 * DD + d];

  const float* ub = u + (size_t)b * TT * RK;
  int t0 = chunk * CS;
  float w0 = phi_raw(ub, t0 - 3, w2r);
  float w1 = phi_raw(ub, t0 - 2, w2r);
  float w2v = phi_raw(ub, t0 - 1, w2r);

  float acc = 0.f;
  for (int i = 0; i < CS; ++i) {
    float pr = phi_raw(ub, t0 + i, w2r);
    float cv = c0 * w0 + c1 * w1 + c2 * w2v + c3 * pr;   // tap j hits input[t-3+j]
    w0 = w1; w1 = w2v; w2v = pr;
    acc += cv;
  }
  csum[(size_t)bc * DD + d] = acc;
}

// ---------------------------------------------------------------------------
// K3: exclusive scan of NC chunk totals per (b,d) channel. 4096 threads.
// ---------------------------------------------------------------------------
__global__ __launch_bounds__(256) void k3_scan(const float* __restrict__ csum,
                                               float* __restrict__ cpre) {
  int idx = blockIdx.x * 256 + threadIdx.x;   // b*DD + d
  int b = idx >> 10;
  int d = idx & (DD - 1);
  float run = 0.f;
  for (int c = 0; c < NC; ++c) {
    size_t o = (size_t)(b * NC + c) * DD + d;
    float v = csum[o];
    cpre[o] = run;
    run += v;
  }
}

// ---------------------------------------------------------------------------
// K4: within-chunk running sum + angle + sincos + RoPE apply + store.
// grid = BB*NC*NH blocks x 64 threads (one pe-lane each).
// ---------------------------------------------------------------------------
__global__ __launch_bounds__(64) void k4_apply(const float* __restrict__ u,
                                               const float* __restrict__ W2,
                                               const float* __restrict__ cw,
                                               const float* __restrict__ cpre,
                                               const float* __restrict__ q,
                                               const float* __restrict__ kk,
                                               float* __restrict__ oq,
                                               float* __restrict__ ok) {
  int p = threadIdx.x;             // 0..63 pe index
  int blk = blockIdx.x;
  int h = blk & 15;
  int bc = blk >> 4;               // b*NC + chunk
  int chunk = bc & (NC - 1);
  int b = bc >> 6;
  int d = h * PE + p;

  float w2r[RK];
#pragma unroll
  for (int r = 0; r < RK; ++r) w2r[r] = W2[r * DD + d];
  float c0 = cw[0 * DD + d], c1 = cw[1 * DD + d];
  float c2 = cw[2 * DD + d], c3 = cw[3 * DD + d];

  // temperature[p] = THETA^(-p/64);  log2(500000) = 18.931568569...
  float temp = exp2f(-(float)p * (18.93156856932417f / 64.f));

  const float* ub = u + (size_t)b * TT * RK;
  float s = cpre[(size_t)bc * DD + d];

  int t0 = chunk * CS;
  float w0 = phi_raw(ub, t0 - 3, w2r);
  float w1 = phi_raw(ub, t0 - 2, w2r);
  float w2v = phi_raw(ub, t0 - 1, w2r);

  int qbase = ((b * TT + t0) * NH + h) * HK + p;
  for (int i = 0; i < CS; ++i) {
    float pr = phi_raw(ub, t0 + i, w2r);
    float cv = c0 * w0 + c1 * w1 + c2 * w2v + c3 * pr;
    w0 = w1; w1 = w2v; w2v = pr;
    s += cv;

    float ang = temp * s;
    float sn, cn;
    __sincosf(ang, &sn, &cn);

    int off = qbase + i * (NH * HK);
    float q0 = q[off], q1 = q[off + PE];
    float k0 = kk[off], k1 = kk[off + PE];
    oq[off]      = q0 * cn - q1 * sn;
    oq[off + PE] = q0 * sn + q1 * cn;
    ok[off]      = k0 * cn - k1 * sn;
    ok[off + PE] = k0 * sn + k1 * cn;
  }
}

extern "C" void kernel_launch(void* const* d_in, const int* in_sizes, int n_in,
                              void* d_out, int out_size, void* d_ws, size_t ws_size,
                              hipStream_t stream) {
  const float* q      = (const float*)d_in[0];
  const float* k      = (const float*)d_in[1];
  const float* hidden = (const float*)d_in[2];
  const float* W1     = (const float*)d_in[3];
  const float* W2     = (const float*)d_in[4];
  const float* convw  = (const float*)d_in[5];
  float* out = (float*)d_out;

  float* u    = (float*)d_ws;                  // BB*TT*RK      = 262144 floats (1 MB)
  float* csum = u + (size_t)BB * TT * RK;      // BB*NC*DD      = 262144 floats (1 MB)
  float* cpre = csum + (size_t)BB * NC * DD;   // BB*NC*DD      = 262144 floats (1 MB)

  k1_u<<<(BB * TT) / 64, 256, 0, stream>>>(hidden, W1, u);
  k2_csum<<<BB * NC * 4, 256, 0, stream>>>(u, W2, convw, csum);
  k3_scan<<<(BB * DD) / 256, 256, 0, stream>>>(csum, cpre);
  k4_apply<<<BB * NC * NH, 64, 0, stream>>>(u, W2, convw, cpre, q, k, out,
                                            out + (size_t)BB * TT * NH * HK);
}

// Round 4
// 579.412 us; speedup vs baseline: 1.3010x; 1.0132x over previous
//
#include <hip/hip_runtime.h>

#define BB 4
#define TT 4096
#define NH 16
#define HK 128
#define PE 64
#define DD 1024      // NH * PE
#define RK 16        // PHI_RANK
#define MD 2048      // MODEL_DIM
#define NC 64        // number of T-chunks
#define CS 64        // chunk size (NC*CS == TT)

// ---------------------------------------------------------------------------
// K1: u[b,t,r] = (per-HEAD-L2-normalized hidden) @ W1     (b*t flat = 16384)
// (unchanged from round 2 — verified correct, ~93 us)
// ---------------------------------------------------------------------------
__global__ __launch_bounds__(256) void k1_u(const float* __restrict__ hidden,
                                            const float* __restrict__ W1,
                                            float* __restrict__ u) {
  __shared__ float hs[4 * 64 * 64];   // 64 KB: per-wave hidden tile, swizzled
  __shared__ float w1t[4 * 64 * RK];  // 16 KB: per-wave W1 row slice

  const int tid  = threadIdx.x;
  const int lane = tid & 63;          // token within block
  const int kg   = tid >> 6;          // wave id = K-group
  const int tok0 = blockIdx.x * 64;

  float* hw = hs  + kg * (64 * 64);
  float* ww = w1t + kg * (64 * RK);
  const int kbase = kg * 512;         // this wave's dim-range start (4 heads)

  float4 hreg[16];
  float4 wreg[4];

  // prologue: issue loads for dc = 0
#pragma unroll
  for (int it = 0; it < 16; ++it) {
    int idx = it * 64 + lane;
    int tr = idx >> 4, q = idx & 15;
    hreg[it] = *(const float4*)(hidden + (size_t)(tok0 + tr) * MD + kbase + q * 4);
  }
#pragma unroll
  for (int it = 0; it < 4; ++it) {
    int idx = it * 64 + lane;
    wreg[it] = *(const float4*)(W1 + (size_t)kbase * RK + idx * 4);
  }

  float ssH = 0.f;                    // current head sum-of-squares
  float accH[RK];                     // current head partial dots
  float accF[RK];                     // normalized accumulated result
#pragma unroll
  for (int r = 0; r < RK; ++r) { accH[r] = 0.f; accF[r] = 0.f; }

  for (int dc = 0; dc < 8; ++dc) {
    // write staged regs to LDS (swizzled: column read later is conflict-free)
#pragma unroll
    for (int it = 0; it < 16; ++it) {
      int idx = it * 64 + lane;
      int tr = idx >> 4, q = idx & 15;
      int base = tr * 64;
      int sw = tr & 31;
      hw[base + ((q * 4 + 0) ^ sw)] = hreg[it].x;
      hw[base + ((q * 4 + 1) ^ sw)] = hreg[it].y;
      hw[base + ((q * 4 + 2) ^ sw)] = hreg[it].z;
      hw[base + ((q * 4 + 3) ^ sw)] = hreg[it].w;
    }
#pragma unroll
    for (int it = 0; it < 4; ++it) {
      int idx = it * 64 + lane;
      *(float4*)(ww + idx * 4) = wreg[it];
    }

    // issue next-tile global loads (overlap with compute below)
    if (dc < 7) {
      const int kb = kbase + (dc + 1) * 64;
#pragma unroll
      for (int it = 0; it < 16; ++it) {
        int idx = it * 64 + lane;
        int tr = idx >> 4, q = idx & 15;
        hreg[it] = *(const float4*)(hidden + (size_t)(tok0 + tr) * MD + kb + q * 4);
      }
#pragma unroll
      for (int it = 0; it < 4; ++it) {
        int idx = it * 64 + lane;
        wreg[it] = *(const float4*)(W1 + (size_t)kb * RK + idx * 4);
      }
    }

    // compute on the LDS tile
    const int sw = lane & 31;
    const float* hrow = hw + lane * 64;
#pragma unroll 8
    for (int d = 0; d < 64; ++d) {
      float e = hrow[d ^ sw];
      ssH += e * e;
      const float4* wr = (const float4*)(ww + d * RK);  // wave-uniform -> broadcast
      float4 w0 = wr[0], w1v = wr[1], w2v = wr[2], w3v = wr[3];
      accH[0]  += e * w0.x;  accH[1]  += e * w0.y;  accH[2]  += e * w0.z;  accH[3]  += e * w0.w;
      accH[4]  += e * w1v.x; accH[5]  += e * w1v.y; accH[6]  += e * w1v.z; accH[7]  += e * w1v.w;
      accH[8]  += e * w2v.x; accH[9]  += e * w2v.y; accH[10] += e * w2v.z; accH[11] += e * w2v.w;
      accH[12] += e * w3v.x; accH[13] += e * w3v.y; accH[14] += e * w3v.z; accH[15] += e * w3v.w;
    }

    // head boundary every 2 tiles (128 dims): apply per-head normalization
    if (dc & 1) {
      float inv = rsqrtf(ssH + 1e-6f);
#pragma unroll
      for (int r = 0; r < RK; ++r) { accF[r] += accH[r] * inv; accH[r] = 0.f; }
      ssH = 0.f;
    }
  }

  // cross-wave reduction (reuse hs; stride 17 -> conflict-free writes)
  __syncthreads();
  float* red = hs;
  {
    float* rp = red + (kg * 64 + lane) * 17;
#pragma unroll
    for (int r = 0; r < RK; ++r) rp[r] = accF[r];
  }
  __syncthreads();
  {
    int tok = tid >> 2, rq = tid & 3;
    float o0 = 0.f, o1 = 0.f, o2 = 0.f, o3 = 0.f;
#pragma unroll
    for (int g = 0; g < 4; ++g) {
      const float* rp = red + (g * 64 + tok) * 17;
      o0 += rp[rq * 4 + 0];
      o1 += rp[rq * 4 + 1];
      o2 += rp[rq * 4 + 2];
      o3 += rp[rq * 4 + 3];
    }
    float4 o = make_float4(o0, o1, o2, o3);
    *(float4*)(u + (size_t)(tok0 + tok) * RK + rq * 4) = o;
  }
}

// dot of one LDS-resident u row (wave-uniform address -> bank broadcast)
__device__ __forceinline__ float phi_lds(const float* __restrict__ us, int j,
                                         const float* __restrict__ w2r) {
  const float4* up = (const float4*)(us + j * RK);
  float4 u0 = up[0], u1 = up[1], u2 = up[2], u3 = up[3];
  return u0.x * w2r[0]  + u0.y * w2r[1]  + u0.z * w2r[2]  + u0.w * w2r[3]
       + u1.x * w2r[4]  + u1.y * w2r[5]  + u1.z * w2r[6]  + u1.w * w2r[7]
       + u2.x * w2r[8]  + u2.y * w2r[9]  + u2.z * w2r[10] + u2.w * w2r[11]
       + u3.x * w2r[12] + u3.y * w2r[13] + u3.z * w2r[14] + u3.w * w2r[15];
}

// cooperative stage of u rows [t0-3 .. t0+63] into LDS (67 rows x 16 floats);
// t<0 rows are zero (causal conv left padding). 256 threads, 268 float4s.
__device__ __forceinline__ void stage_u(const float* __restrict__ ub, int t0,
                                        float* __restrict__ us, int tid) {
  for (int idx = tid; idx < 67 * 4; idx += 256) {
    int j = idx >> 2, rq = idx & 3;
    int t = t0 - 3 + j;
    float4 v = make_float4(0.f, 0.f, 0.f, 0.f);
    if (t >= 0) v = *(const float4*)(ub + (size_t)t * RK + rq * 4);
    *(float4*)(us + j * RK + rq * 4) = v;
  }
  __syncthreads();
}

// ---------------------------------------------------------------------------
// K2: per-chunk totals of phi_conv over each CS-length chunk.
// grid = BB*NC*4 blocks x 256 threads; thread owns one d channel.
// u rows for the chunk staged once in LDS; inner loop is LDS-broadcast reads.
// ---------------------------------------------------------------------------
__global__ __launch_bounds__(256) void k2_csum(const float* __restrict__ u,
                                               const float* __restrict__ W2,
                                               const float* __restrict__ cw,
                                               float* __restrict__ csum) {
  __shared__ float us[67 * RK];       // 4.3 KB

  int tid = threadIdx.x;
  int blk = blockIdx.x;
  int dblk = blk & 3;
  int bc = blk >> 2;               // b*NC + chunk
  int chunk = bc & (NC - 1);
  int b = bc >> 6;
  int d = dblk * 256 + tid;
  int t0 = chunk * CS;

  stage_u(u + (size_t)b * TT * RK, t0, us, tid);

  float w2r[RK];
#pragma unroll
  for (int r = 0; r < RK; ++r) w2r[r] = W2[r * DD + d];
  float c0 = cw[0 * DD + d], c1 = cw[1 * DD + d];
  float c2 = cw[2 * DD + d], c3 = cw[3 * DD + d];

  float w0 = phi_lds(us, 0, w2r);
  float w1 = phi_lds(us, 1, w2r);
  float w2v = phi_lds(us, 2, w2r);

  float acc = 0.f;
#pragma unroll 4
  for (int i = 0; i < CS; ++i) {
    float pr = phi_lds(us, i + 3, w2r);
    float cv = c0 * w0 + c1 * w1 + c2 * w2v + c3 * pr;   // tap j hits input[t-3+j]
    w0 = w1; w1 = w2v; w2v = pr;
    acc += cv;
  }
  csum[(size_t)bc * DD + d] = acc;
}

// ---------------------------------------------------------------------------
// K3: exclusive scan of NC chunk totals per (b,d) channel. 4096 threads.
// 8-wide load batching so 8 loads are in flight per step.
// ---------------------------------------------------------------------------
__global__ __launch_bounds__(256) void k3_scan(const float* __restrict__ csum,
                                               float* __restrict__ cpre) {
  int idx = blockIdx.x * 256 + threadIdx.x;   // b*DD + d
  int b = idx >> 10;
  int d = idx & (DD - 1);
  size_t o = (size_t)b * NC * DD + d;
  float run = 0.f;
  for (int c = 0; c < NC; c += 8) {
    float v0 = csum[o + 0 * DD], v1 = csum[o + 1 * DD];
    float v2 = csum[o + 2 * DD], v3 = csum[o + 3 * DD];
    float v4 = csum[o + 4 * DD], v5 = csum[o + 5 * DD];
    float v6 = csum[o + 6 * DD], v7 = csum[o + 7 * DD];
    cpre[o + 0 * DD] = run; run += v0;
    cpre[o + 1 * DD] = run; run += v1;
    cpre[o + 2 * DD] = run; run += v2;
    cpre[o + 3 * DD] = run; run += v3;
    cpre[o + 4 * DD] = run; run += v4;
    cpre[o + 5 * DD] = run; run += v5;
    cpre[o + 6 * DD] = run; run += v6;
    cpre[o + 7 * DD] = run; run += v7;
    o += 8 * (size_t)DD;
  }
}

// ---------------------------------------------------------------------------
// K4: within-chunk running sum + angle + sincos + RoPE apply + store.
// grid = BB*NC*4 blocks x 256 threads; wave w = head (blk&3)*4+w, lane = pe.
// u rows staged once per block (shared by 4 waves); q/k prefetched one
// iteration ahead so global latency hides under phi+sincos+rope.
// ---------------------------------------------------------------------------
__global__ __launch_bounds__(256) void k4_apply(const float* __restrict__ u,
                                                const float* __restrict__ W2,
                                                const float* __restrict__ cw,
                                                const float* __restrict__ cpre,
                                                const float* __restrict__ q,
                                                const float* __restrict__ kk,
                                                float* __restrict__ oq,
                                                float* __restrict__ ok) {
  __shared__ float us[67 * RK];       // 4.3 KB

  int tid = threadIdx.x;
  int lane = tid & 63;
  int wave = tid >> 6;
  int blk = blockIdx.x;
  int hq = blk & 3;
  int bc = blk >> 2;               // b*NC + chunk
  int chunk = bc & (NC - 1);
  int b = bc >> 6;
  int h = hq * 4 + wave;
  int p = lane;
  int d = h * PE + p;
  int t0 = chunk * CS;

  stage_u(u + (size_t)b * TT * RK, t0, us, tid);

  float w2r[RK];
#pragma unroll
  for (int r = 0; r < RK; ++r) w2r[r] = W2[r * DD + d];
  float c0 = cw[0 * DD + d], c1 = cw[1 * DD + d];
  float c2 = cw[2 * DD + d], c3 = cw[3 * DD + d];

  // temperature[p] = THETA^(-p/64);  log2(500000) = 18.931568569...
  float temp = exp2f(-(float)p * (18.93156856932417f / 64.f));

  float s = cpre[(size_t)bc * DD + d];

  float w0 = phi_lds(us, 0, w2r);
  float w1 = phi_lds(us, 1, w2r);
  float w2v = phi_lds(us, 2, w2r);

  int off = ((b * TT + t0) * NH + h) * HK + p;
  float q0 = q[off], q1 = q[off + PE];
  float k0 = kk[off], k1 = kk[off + PE];

  for (int i = 0; i < CS; ++i) {
    // prefetch next token's q/k (uniform branch; hides under compute below)
    float q0n = 0.f, q1n = 0.f, k0n = 0.f, k1n = 0.f;
    int offn = off + NH * HK;
    if (i + 1 < CS) {
      q0n = q[offn]; q1n = q[offn + PE];
      k0n = kk[offn]; k1n = kk[offn + PE];
    }

    float pr = phi_lds(us, i + 3, w2r);
    float cv = c0 * w0 + c1 * w1 + c2 * w2v + c3 * pr;
    w0 = w1; w1 = w2v; w2v = pr;
    s += cv;

    float ang = temp * s;
    float sn, cn;
    __sincosf(ang, &sn, &cn);

    oq[off]      = q0 * cn - q1 * sn;
    oq[off + PE] = q0 * sn + q1 * cn;
    ok[off]      = k0 * cn - k1 * sn;
    ok[off + PE] = k0 * sn + k1 * cn;

    q0 = q0n; q1 = q1n; k0 = k0n; k1 = k1n;
    off = offn;
  }
}

extern "C" void kernel_launch(void* const* d_in, const int* in_sizes, int n_in,
                              void* d_out, int out_size, void* d_ws, size_t ws_size,
                              hipStream_t stream) {
  const float* q      = (const float*)d_in[0];
  const float* k      = (const float*)d_in[1];
  const float* hidden = (const float*)d_in[2];
  const float* W1     = (const float*)d_in[3];
  const float* W2     = (const float*)d_in[4];
  const float* convw  = (const float*)d_in[5];
  float* out = (float*)d_out;

  float* u    = (float*)d_ws;                  // BB*TT*RK      = 262144 floats (1 MB)
  float* csum = u + (size_t)BB * TT * RK;      // BB*NC*DD      = 262144 floats (1 MB)
  float* cpre = csum + (size_t)BB * NC * DD;   // BB*NC*DD      = 262144 floats (1 MB)

  k1_u<<<(BB * TT) / 64, 256, 0, stream>>>(hidden, W1, u);
  k2_csum<<<BB * NC * 4, 256, 0, stream>>>(u, W2, convw, csum);
  k3_scan<<<(BB * DD) / 256, 256, 0, stream>>>(csum, cpre);
  k4_apply<<<BB * NC * 4, 256, 0, stream>>>(u, W2, convw, cpre, q, k, out,
                                            out + (size_t)BB * TT * NH * HK);
}